// Round 18
// baseline (4230.899 us; speedup 1.0000x reference)
//
#include <hip/hip_runtime.h>
#include <hip/hip_fp16.h>

// Persistent 2D-LSTM, tagged-ring protocol + 2-group interleave (r18).
// B=64, NC=512, T=1024, K=1216 = [x 0..191 | h(t-32) 192..703 | h(t-1) 704..1215].
// 128 WGs x 512 thr: set s=bid>>6 serves groups {2s,2s+1} (16 batches each),
// WG w=bid&63 owns channels w*8..+7 (x4 gates). Two sub-steps per step:
// group A's publish->visibility RTT hides under group B's compute and vice
// versa. Pointwise: waves 0-1 do A, waves 2-3 do B. h32/x prefetched per
// group mid-own-sub-step (raw, validated at use one step later; 31-step-old
// data => never premature). Consume polls blocking-at-consume (r6 semantics).
// Ring FRAGMENT-MAJOR (r14): per (slot,g) block of 2048 u64,
//   u64 idx = chunk*128 + 2*lane (+0/+1). Tags: fp16 LSB = ((t>>6)&1).

typedef __attribute__((ext_vector_type(8))) _Float16 half8;
typedef __attribute__((ext_vector_type(4))) float f32x4;
typedef unsigned long long u64;

#define T_ 1024

#define LDS_W    77824              // 38 chunks * 2 tiles * 64 lanes * 16B
#define LDS_PSM  33792              // f32 [2][8][16][33]
#define LDS_ALL  (LDS_W + LDS_PSM + 1024)

extern __shared__ char smem[];

union U2H { u64 u[2]; half8 h; };

__global__ __launch_bounds__(512, 1) void lstm_persist(
    const float* __restrict__ x, const float* __restrict__ Wih,
    const float* __restrict__ Whh, const float* __restrict__ bih,
    const float* __restrict__ bhh, float* __restrict__ out,
    u64* ring)
{
    _Float16* Wsm = (_Float16*)smem;
    float*    Psm = (float*)(smem + LDS_W);
    float*    cst = (float*)(smem + LDS_W + LDS_PSM);   // [256]: A=0..127, B=128..255

    const int tid = threadIdx.x;
    const int l   = tid & 63, wv = tid >> 6;
    const int l15 = l & 15,  l4 = l >> 4;
    const int bid = blockIdx.x;
    const int st  = bid >> 6;          // set 0..1
    const int w   = bid & 63;          // channel WG 0..63
    const int gA  = st * 2, gB = st * 2 + 1;

    // ---- weights fp32 -> fp16 fragments in LDS (once) ----
    for (int p = wv; p < 76; p += 8) {
        const int c = p >> 1, nb = p & 1;
        const int rj = (l15 & 3) * 512 + w * 8 + nb * 4 + (l15 >> 2);
        const int k  = c * 32 + l4 * 8;
        const float* src = (c < 22) ? (Wih + (size_t)rj * 704 + k)
                                    : (Whh + (size_t)rj * 512 + (k - 704));
        float4 v0 = ((const float4*)src)[0];
        float4 v1 = ((const float4*)src)[1];
        half8 hb;
        hb[0]=(_Float16)v0.x; hb[1]=(_Float16)v0.y; hb[2]=(_Float16)v0.z; hb[3]=(_Float16)v0.w;
        hb[4]=(_Float16)v1.x; hb[5]=(_Float16)v1.y; hb[6]=(_Float16)v1.z; hb[7]=(_Float16)v1.w;
        *(half8*)(Wsm + (size_t)((c * 2 + nb) * 64 + l) * 8) = hb;
    }
    if (tid < 256) cst[tid] = 0.f;

    const int pcb = tid & 7;            // pointwise channel (valid for tid<256)
    const int gcb = w * 8 + pcb;
    const float bI = bih[gcb]        + bhh[gcb];
    const float bF = bih[512 + gcb]  + bhh[512 + gcb];
    const float bG = bih[1024 + gcb] + bhh[1024 + gcb];
    const float bO = bih[1536 + gcb] + bhh[1536 + gcb];
    __syncthreads();

    // per-wave chunk ownership
    const int coff = (wv + 2) & 7;
    const int c32a = 6 + coff,  c32b = 14 + coff;
    const int c1a  = 22 + coff, c1b  = 30 + coff;
    const int gbA  = gA * 16 + l15, gbB = gB * 16 + l15;

    auto wfrag = [&](int c, int nb) -> half8 {
        return *(const half8*)(Wsm + (size_t)((c * 2 + nb) * 64 + l) * 8);
    };
    auto rld = [&](size_t i) -> u64 {
        return __hip_atomic_load(ring + i, __ATOMIC_RELAXED, __HIP_MEMORY_SCOPE_AGENT);
    };
    auto ridx = [&](int slot, int g_, int cc) -> size_t {
        return ((size_t)(slot * 4 + g_)) * 2048 + (size_t)cc * 128 + 2 * l;
    };
    const u64 TM = 0x0001000100010001ULL;

    // blocking tagged chunk load (consume path; detect == data-in-hand)
    auto loadfrag = [&](int slot, int g_, int cc, unsigned par_) -> half8 {
        const size_t idx = ridx(slot, g_, cc);
        const u64 ex = par_ ? TM : 0ULL;
        u64 v0 = rld(idx), v1 = rld(idx + 1);
        bool ok = ((v0 & TM) == ex) && ((v1 & TM) == ex);
        while (!__all(ok)) {
            __builtin_amdgcn_s_sleep(1);
            if (!ok) {
                v0 = rld(idx); v1 = rld(idx + 1);
                ok = ((v0 & TM) == ex) && ((v1 & TM) == ex);
            }
        }
        U2H cc_; cc_.u[0] = v0; cc_.u[1] = v1;
        return cc_.h;
    };

    auto xload = [&](int gb_, int t_, float4& r0, float4& r1) {
        const int yn = t_ >> 5, xcn = t_ & 31;
        const int k0 = wv * 32 + l4 * 8;
        const float* xs = x + ((size_t)(gb_ * 3 + (k0 >> 6)) * 256
                               + yn * 8 + ((k0 >> 3) & 7)) * 256 + xcn * 8;
        r0 = ((const float4*)xs)[0];
        r1 = ((const float4*)xs)[1];
    };
    auto xmfma = [&](float4 v0, float4 v1, f32x4& a0, f32x4& a1) {
        half8 a;
        a[0]=(_Float16)v0.x; a[1]=(_Float16)v0.y; a[2]=(_Float16)v0.z; a[3]=(_Float16)v0.w;
        a[4]=(_Float16)v1.x; a[5]=(_Float16)v1.y; a[6]=(_Float16)v1.z; a[7]=(_Float16)v1.w;
        a0 = __builtin_amdgcn_mfma_f32_16x16x32_f16(a, wfrag(wv,0), a0, 0,0,0);
        a1 = __builtin_amdgcn_mfma_f32_16x16x32_f16(a, wfrag(wv,1), a1, 0,0,0);
    };
    // validate raw-prefetched h32 regs (rare retry), then 4 MFMAs
    auto h32part = [&](int t, int g_, u64& a0_, u64& a1_, u64& b0_, u64& b1_,
                       f32x4& A0, f32x4& A1) {
        const u64 ex = (((t - 32) >> 6) & 1) ? TM : 0ULL;
        bool ok = ((a0_ & TM) == ex) && ((a1_ & TM) == ex) &&
                  ((b0_ & TM) == ex) && ((b1_ & TM) == ex);
        if (!__all(ok)) {
            const size_t ia = ridx((t - 32) & 63, g_, c32a - 6);
            const size_t ib = ridx((t - 32) & 63, g_, c32b - 6);
            do {
                __builtin_amdgcn_s_sleep(1);
                if (!ok) {
                    a0_ = rld(ia); a1_ = rld(ia + 1);
                    b0_ = rld(ib); b1_ = rld(ib + 1);
                    ok = ((a0_ & TM) == ex) && ((a1_ & TM) == ex) &&
                         ((b0_ & TM) == ex) && ((b1_ & TM) == ex);
                }
            } while (!__all(ok));
        }
        U2H ca, cb;
        ca.u[0] = a0_; ca.u[1] = a1_; cb.u[0] = b0_; cb.u[1] = b1_;
        A0 = __builtin_amdgcn_mfma_f32_16x16x32_f16(ca.h, wfrag(c32a,0), A0, 0,0,0);
        A1 = __builtin_amdgcn_mfma_f32_16x16x32_f16(ca.h, wfrag(c32a,1), A1, 0,0,0);
        A0 = __builtin_amdgcn_mfma_f32_16x16x32_f16(cb.h, wfrag(c32b,0), A0, 0,0,0);
        A1 = __builtin_amdgcn_mfma_f32_16x16x32_f16(cb.h, wfrag(c32b,1), A1, 0,0,0);
    };
    auto h1part = [&](int t, int g_, f32x4& A0, f32x4& A1) {
        const int sP = (t - 1) & 63;
        const unsigned p1 = ((t - 1) >> 6) & 1;
        half8 ha = loadfrag(sP, g_, c1a - 22, p1);
        A0 = __builtin_amdgcn_mfma_f32_16x16x32_f16(ha, wfrag(c1a,0), A0, 0,0,0);
        A1 = __builtin_amdgcn_mfma_f32_16x16x32_f16(ha, wfrag(c1a,1), A1, 0,0,0);
        half8 hb = loadfrag(sP, g_, c1b - 22, p1);
        A0 = __builtin_amdgcn_mfma_f32_16x16x32_f16(hb, wfrag(c1b,0), A0, 0,0,0);
        A1 = __builtin_amdgcn_mfma_f32_16x16x32_f16(hb, wfrag(c1b,1), A1, 0,0,0);
    };
    auto psmwrite = [&](int sub, f32x4 A0, f32x4 A1) {
        float* Pw = Psm + (size_t)((sub * 8 + wv) * 16) * 33;
#pragma unroll
        for (int r = 0; r < 4; ++r) {
            Pw[(l4 * 4 + r) * 33 + l15]      = A0[r];
            Pw[(l4 * 4 + r) * 33 + 16 + l15] = A1[r];
        }
    };
    auto pointwise = [&](int t, int g_, int sub, int tl) {
        float gi = bI, gf = bF, gg = bG, go = bO;
        const int pb_ = tl >> 3, pc_ = tl & 7;
#pragma unroll
        for (int q = 0; q < 8; ++q) {
            const float* Pq = Psm + ((size_t)((sub * 8 + q) * 16 + pb_)) * 33 + pc_ * 4;
            gi += Pq[0]; gf += Pq[1]; gg += Pq[2]; go += Pq[3];
        }
        const float cprev = cst[tid];
        const float si = 1.f / (1.f + __expf(-gi));
        const float sf = 1.f / (1.f + __expf(-gf));
        const float so = 1.f / (1.f + __expf(-go));
        const float tg = 2.f / (1.f + __expf(-2.f * gg)) - 1.f;
        const float cn = sf * cprev + si * tg;
        const float th = 2.f / (1.f + __expf(-2.f * cn)) - 1.f;
        const float hn = so * th;
        cst[tid] = cn;

        union { _Float16 f; unsigned short s; } cv; cv.f = (_Float16)hn;
        unsigned hb16 = ((unsigned)cv.s & ~1u) | (unsigned)((t >> 6) & 1);
        unsigned other = (unsigned)__shfl_xor((int)hb16, 1);
        unsigned pairv = (pc_ & 1) ? ((other & 0xffffu) | (hb16 << 16))
                                   : ((hb16 & 0xffffu) | (other << 16));
        unsigned hi = (unsigned)__shfl_xor((int)pairv, 2);
        if ((pc_ & 3) == 0) {
            u64 val = (u64)pairv | ((u64)hi << 32);
            const size_t idx = ((size_t)((t & 63) * 4 + g_)) * 2048
                             + (size_t)w * 32 + (size_t)pb_ * 2 + (pc_ >> 2);
            __hip_atomic_store(ring + idx, val, __ATOMIC_RELAXED,
                               __HIP_MEMORY_SCOPE_AGENT);
        }
        out[(size_t)(g_ * 16 + pb_) * (T_ * 512) + (size_t)t * 512 + w * 8 + pc_] = hn;
    };

    // prefetch register state
    float4 xaA0, xaA1, xaB0, xaB1;
    u64 hAa0=0,hAa1=0,hAb0=0,hAb1=0;   // group A h(t-32) raw
    u64 hBa0=0,hBa1=0,hBb0=0,hBb1=0;   // group B h(t-32) raw

    if (wv < 6) { xload(gbA, 0, xaA0, xaA1); xload(gbB, 0, xaB0, xaB1); }

    for (int t = 0; t < T_; ++t) {
        const int tn = t + 1;

        // ======== sub-step A (group gA) ========
        f32x4 acc0 = {0.f,0.f,0.f,0.f}, acc1 = {0.f,0.f,0.f,0.f};
        if (wv < 6) xmfma(xaA0, xaA1, acc0, acc1);
        if (t >= 32) h32part(t, gA, hAa0, hAa1, hAb0, hAb1, acc0, acc1);
        if (t > 0)  h1part(t, gA, acc0, acc1);
        // [P_A] prefetch group A's t+1 inputs (raw; validated at next use)
        if (tn < T_) {
            if (wv < 6) xload(gbA, tn, xaA0, xaA1);
            if (tn >= 32) {
                const size_t ia = ridx((tn - 32) & 63, gA, c32a - 6);
                const size_t ib = ridx((tn - 32) & 63, gA, c32b - 6);
                hAa0 = rld(ia); hAa1 = rld(ia + 1);
                hAb0 = rld(ib); hAb1 = rld(ib + 1);
            }
        }
        psmwrite(0, acc0, acc1);
        __syncthreads();
        if (tid < 128) pointwise(t, gA, 0, tid);

        // ======== sub-step B (group gB) ========
        acc0 = (f32x4){0.f,0.f,0.f,0.f}; acc1 = (f32x4){0.f,0.f,0.f,0.f};
        if (wv < 6) xmfma(xaB0, xaB1, acc0, acc1);
        if (t >= 32) h32part(t, gB, hBa0, hBa1, hBb0, hBb1, acc0, acc1);
        if (t > 0)  h1part(t, gB, acc0, acc1);
        // [P_B] prefetch group B's t+1 inputs
        if (tn < T_) {
            if (wv < 6) xload(gbB, tn, xaB0, xaB1);
            if (tn >= 32) {
                const size_t ia = ridx((tn - 32) & 63, gB, c32a - 6);
                const size_t ib = ridx((tn - 32) & 63, gB, c32b - 6);
                hBa0 = rld(ia); hBa1 = rld(ia + 1);
                hBb0 = rld(ib); hBb1 = rld(ib + 1);
            }
        }
        psmwrite(1, acc0, acc1);
        __syncthreads();
        if (tid >= 128 && tid < 256) pointwise(t, gB, 1, tid - 128);
    }
}

extern "C" void kernel_launch(void* const* d_in, const int* in_sizes, int n_in,
                              void* d_out, int out_size, void* d_ws, size_t ws_size,
                              hipStream_t stream) {
    const float* x   = (const float*)d_in[0];
    const float* Wih = (const float*)d_in[1];
    const float* Whh = (const float*)d_in[2];
    const float* bih = (const float*)d_in[3];
    const float* bhh = (const float*)d_in[4];
    float* out = (float*)d_out;

    u64* ring = (u64*)d_ws;   // 64*4*2048 u64 = 4 MB

    // LSB pattern 1 everywhere != gen-0 parity 0
    hipMemsetAsync(ring, 0x01, 64ull * 4 * 2048 * 8, stream);

    (void)hipFuncSetAttribute((const void*)lstm_persist,
                              hipFuncAttributeMaxDynamicSharedMemorySize, LDS_ALL);

    hipLaunchKernelGGL(lstm_persist, dim3(128), dim3(512), LDS_ALL, stream,
                       x, Wih, Whh, bih, bhh, out, ring);
}

// Round 19
// 2457.964 us; speedup vs baseline: 1.7213x; 1.7213x over previous
//
#include <hip/hip_runtime.h>
#include <hip/hip_fp16.h>

// Persistent 2D-LSTM, self-validating tagged-ring protocol (no fences/flags).
// B=64, NC=512, T=1024, K=1216 = [x 0..191 | h(t-32) 192..703 | h(t-1) 704..1215].
// 4 batch-groups x 64 col-WGs = 256 WGs x 512 thr (1 WG/CU, 112KB LDS).
// WG (g,w): batches g*16..+15, channels w*8..+7 (x4 gates = 32 gate-cols).
// Ring FRAGMENT-MAJOR (r14): per (slot,g) block of 2048 u64,
//   u64 idx = chunk*128 + 2*lane (+0/+1) -> wave reads 1KB contiguous.
// Tags: each fp16 LSB = generation parity ((t>>6)&1); pre-memset 0x01.
// r19: h(t-32) round-0 consume = NORMAL CACHEABLE 16B loads -- data is 31
// steps old (never premature), lines never tainted (h1 reads bypass L2), so
// the 8 WGs/XCD of a group share one MALL fetch through their L2 (8x dedup
// on half the consume traffic). h(t-1) round-0 + ALL retries stay sc0 sc1
// (MALL-direct): r15 proved h1 cacheable round-0 poisons L2 via premature
// polls. Publish: packed 16B sc0 sc1 stores (r17).

typedef __attribute__((ext_vector_type(8))) _Float16 half8;
typedef __attribute__((ext_vector_type(4))) float f32x4;
typedef __attribute__((ext_vector_type(4))) unsigned u32x4;
typedef unsigned long long u64;

#define T_ 1024

#define LDS_W    77824              // 38 chunks * 2 tiles * 64 lanes * 16B
#define LDS_PSM  33792              // f32 [2][8][16][33]
#define LDS_ALL  (LDS_W + LDS_PSM + 512)

extern __shared__ char smem[];

__global__ __launch_bounds__(512, 1) void lstm_persist(
    const float* __restrict__ x, const float* __restrict__ Wih,
    const float* __restrict__ Whh, const float* __restrict__ bih,
    const float* __restrict__ bhh, float* __restrict__ out,
    u64* ring)
{
    _Float16* Wsm = (_Float16*)smem;
    float*    Psm = (float*)(smem + LDS_W);
    float*    cst = (float*)(smem + LDS_W + LDS_PSM);

    const int tid = threadIdx.x;
    const int l   = tid & 63, wv = tid >> 6;
    const int l15 = l & 15,  l4 = l >> 4;
    const int bid = blockIdx.x;
    const int g   = bid >> 6;          // batch group 0..3
    const int w   = bid & 63;          // channel WG 0..63

    // ---- weights fp32 -> fp16 fragments in LDS (once) ----
    // tile col co = nb*16 + l15: gate = l15&3, ch_local = nb*4 + (l15>>2)
    for (int p = wv; p < 76; p += 8) {
        const int c = p >> 1, nb = p & 1;
        const int rj = (l15 & 3) * 512 + w * 8 + nb * 4 + (l15 >> 2);
        const int k  = c * 32 + l4 * 8;
        const float* src = (c < 22) ? (Wih + (size_t)rj * 704 + k)
                                    : (Whh + (size_t)rj * 512 + (k - 704));
        float4 v0 = ((const float4*)src)[0];
        float4 v1 = ((const float4*)src)[1];
        half8 hb;
        hb[0]=(_Float16)v0.x; hb[1]=(_Float16)v0.y; hb[2]=(_Float16)v0.z; hb[3]=(_Float16)v0.w;
        hb[4]=(_Float16)v1.x; hb[5]=(_Float16)v1.y; hb[6]=(_Float16)v1.z; hb[7]=(_Float16)v1.w;
        *(half8*)(Wsm + (size_t)((c * 2 + nb) * 64 + l) * 8) = hb;
    }
    if (tid < 128) cst[tid] = 0.f;

    // pointwise role (tid<128): pb = batch 0..15, pc = channel 0..7
    const int pb = tid >> 3, pc = tid & 7;
    const int gc = w * 8 + pc;
    const float bI = bih[gc]        + bhh[gc];
    const float bF = bih[512 + gc]  + bhh[512 + gc];
    const float bG = bih[1024 + gc] + bhh[1024 + gc];
    const float bO = bih[1536 + gc] + bhh[1536 + gc];
    __syncthreads();

    // per-wave chunk ownership: all c in 0..37 with c%8 == wv
    const int coff = (wv + 2) & 7;
    const int c32a = 6 + coff,  c32b = 14 + coff;   // h(t-32) chunks
    const int c1a  = 22 + coff, c1b  = 30 + coff;   // h(t-1) chunks
    const int gb   = g * 16 + l15;                  // A-row batch

    auto wfrag = [&](int c, int nb) -> half8 {
        return *(const half8*)(Wsm + (size_t)((c * 2 + nb) * 64 + l) * 8);
    };
    // dual 16B loads: MALL-direct (sc0 sc1) variant
    auto ld2_sc = [&](const u64* pa, const u64* pb_, u32x4& ra, u32x4& rb) {
        asm volatile(
            "global_load_dwordx4 %0, %2, off sc0 sc1\n\t"
            "global_load_dwordx4 %1, %3, off sc0 sc1\n\t"
            "s_waitcnt vmcnt(0)"
            : "=&v"(ra), "=&v"(rb)
            : "v"(pa), "v"(pb_)
            : "memory");
    };
    // dual 16B loads: normal cacheable variant (L2-dedup across WGs on XCD)
    auto ld2_ca = [&](const u64* pa, const u64* pb_, u32x4& ra, u32x4& rb) {
        asm volatile(
            "global_load_dwordx4 %0, %2, off\n\t"
            "global_load_dwordx4 %1, %3, off\n\t"
            "s_waitcnt vmcnt(0)"
            : "=&v"(ra), "=&v"(rb)
            : "v"(pa), "v"(pb_)
            : "memory");
    };
    auto tagok = [&](u32x4 r, unsigned ex) -> bool {
        const unsigned m = 0x00010001u;
        return ((r[0] & m) == ex) && ((r[1] & m) == ex) &&
               ((r[2] & m) == ex) && ((r[3] & m) == ex);
    };
    // fused dual-chunk tagged load; cached0 picks round-0 path; retries sc.
    auto loadfrag2x = [&](int slot, int cc0, int cc1, unsigned par_, bool cached0,
                          half8& h0, half8& h1) {
        const size_t blk = ((size_t)(slot * 4 + g)) * 2048 + 2 * l;
        const u64* pa = ring + blk + (size_t)cc0 * 128;
        const u64* pb_ = ring + blk + (size_t)cc1 * 128;
        const unsigned ex = par_ ? 0x00010001u : 0u;
        u32x4 ra, rb;
        if (cached0) ld2_ca(pa, pb_, ra, rb);
        else         ld2_sc(pa, pb_, ra, rb);
        bool ok = tagok(ra, ex) && tagok(rb, ex);
        while (!__all(ok)) {
            __builtin_amdgcn_s_sleep(1);
            if (!ok) {
                ld2_sc(pa, pb_, ra, rb);
                ok = tagok(ra, ex) && tagok(rb, ex);
            }
        }
        union { u32x4 v; half8 h; } ca, cb;
        ca.v = ra; cb.v = rb;
        h0 = ca.h; h1 = cb.h;
    };

    float4 xa0, xa1;
    half8  h32a, h32b;
    if (wv < 6) {   // x prefetch for t=0 (y=0, xc=0)
        const int k0 = wv * 32 + l4 * 8;
        const float* xs = x + ((size_t)(gb * 3 + (k0 >> 6)) * 256 + ((k0 >> 3) & 7)) * 256;
        xa0 = ((const float4*)xs)[0];
        xa1 = ((const float4*)xs)[1];
    }

    for (int t = 0; t < T_; ++t) {
        const int par = t & 1;
        f32x4 acc0 = {0.f,0.f,0.f,0.f}, acc1 = {0.f,0.f,0.f,0.f};

        // [A] x part (prefetched regs)
        if (wv < 6) {
            half8 a;
            a[0]=(_Float16)xa0.x; a[1]=(_Float16)xa0.y; a[2]=(_Float16)xa0.z; a[3]=(_Float16)xa0.w;
            a[4]=(_Float16)xa1.x; a[5]=(_Float16)xa1.y; a[6]=(_Float16)xa1.z; a[7]=(_Float16)xa1.w;
            acc0 = __builtin_amdgcn_mfma_f32_16x16x32_f16(a, wfrag(wv,0), acc0, 0,0,0);
            acc1 = __builtin_amdgcn_mfma_f32_16x16x32_f16(a, wfrag(wv,1), acc1, 0,0,0);
        }
        // [B] h(t-32) part (prefetched regs)
        if (t >= 32) {
            acc0 = __builtin_amdgcn_mfma_f32_16x16x32_f16(h32a, wfrag(c32a,0), acc0, 0,0,0);
            acc1 = __builtin_amdgcn_mfma_f32_16x16x32_f16(h32a, wfrag(c32a,1), acc1, 0,0,0);
            acc0 = __builtin_amdgcn_mfma_f32_16x16x32_f16(h32b, wfrag(c32b,0), acc0, 0,0,0);
            acc1 = __builtin_amdgcn_mfma_f32_16x16x32_f16(h32b, wfrag(c32b,1), acc1, 0,0,0);
        }
        // [C] h(t-1): fused dual-chunk tagged wait (MALL-direct) + 4 MFMAs
        if (t > 0) {
            const int sP = (t - 1) & 63;
            const unsigned p1 = ((t - 1) >> 6) & 1;
            half8 ha, hb;
            loadfrag2x(sP, c1a - 22, c1b - 22, p1, false, ha, hb);
            acc0 = __builtin_amdgcn_mfma_f32_16x16x32_f16(ha, wfrag(c1a,0), acc0, 0,0,0);
            acc1 = __builtin_amdgcn_mfma_f32_16x16x32_f16(ha, wfrag(c1a,1), acc1, 0,0,0);
            acc0 = __builtin_amdgcn_mfma_f32_16x16x32_f16(hb, wfrag(c1b,0), acc0, 0,0,0);
            acc1 = __builtin_amdgcn_mfma_f32_16x16x32_f16(hb, wfrag(c1b,1), acc1, 0,0,0);
        }

        // [Px] x prefetch for t+1 (plain loads; flight window = [D]+[E]+[F])
        const int tn = t + 1;
        if (tn < T_ && wv < 6) {
            const int yn = tn >> 5, xcn = tn & 31;
            const int k0 = wv * 32 + l4 * 8;
            const float* xs = x + ((size_t)(gb * 3 + (k0 >> 6)) * 256
                                   + yn * 8 + ((k0 >> 3) & 7)) * 256 + xcn * 8;
            xa0 = ((const float4*)xs)[0];
            xa1 = ((const float4*)xs)[1];
        }

        // [D] partials -> LDS (parity double-buffer)
        {
            float* Pw = Psm + (size_t)((par * 8 + wv) * 16) * 33;
#pragma unroll
            for (int r = 0; r < 4; ++r) {
                Pw[(l4 * 4 + r) * 33 + l15]      = acc0[r];
                Pw[(l4 * 4 + r) * 33 + 16 + l15] = acc1[r];
            }
        }
        __syncthreads();   // [E] the only barrier per step

        // [F] pointwise + packed 16B publish (waves 0-1); waves 2-7 run ahead
        if (tid < 128) {
            float gi = bI, gf = bF, gg = bG, go = bO;
#pragma unroll
            for (int q = 0; q < 8; ++q) {
                const float* Pq = Psm + ((size_t)((par * 8 + q) * 16 + pb)) * 33 + pc * 4;
                gi += Pq[0]; gf += Pq[1]; gg += Pq[2]; go += Pq[3];
            }
            const float cprev = cst[tid];
            const float si = 1.f / (1.f + __expf(-gi));
            const float sf = 1.f / (1.f + __expf(-gf));
            const float so = 1.f / (1.f + __expf(-go));
            const float tg = 2.f / (1.f + __expf(-2.f * gg)) - 1.f;
            const float cn = sf * cprev + si * tg;
            const float th = 2.f / (1.f + __expf(-2.f * cn)) - 1.f;
            const float hn = so * th;
            cst[tid] = cn;

            union { _Float16 f; unsigned short s; } cv; cv.f = (_Float16)hn;
            unsigned hb16 = ((unsigned)cv.s & ~1u) | (unsigned)((t >> 6) & 1);  // force tag
            unsigned other = (unsigned)__shfl_xor((int)hb16, 1);
            unsigned pairv = (pc & 1) ? ((other & 0xffffu) | (hb16 << 16))
                                      : ((hb16 & 0xffffu) | (other << 16));
            unsigned hi  = (unsigned)__shfl_xor((int)pairv, 2);
            unsigned pv4 = (unsigned)__shfl_xor((int)pairv, 4);
            unsigned hi4 = (unsigned)__shfl_xor((int)hi, 4);
            if (pc == 0) {
                u32x4 val;
                val[0] = pairv; val[1] = hi;     // u64 for ch 0..3
                val[2] = pv4;   val[3] = hi4;    // u64 for ch 4..7
                const u64* dst = ring + ((size_t)((t & 63) * 4 + g)) * 2048
                               + (size_t)w * 32 + (size_t)pb * 2;
                asm volatile("global_store_dwordx4 %0, %1, off sc0 sc1"
                             :: "v"(dst), "v"(val) : "memory");
            }
            out[(size_t)(g * 16 + pb) * (T_ * 512) + (size_t)t * 512 + gc] = hn;
        }

        // [G/H] h(t+1-32) prefetch: CACHEABLE round-0 (31 steps old, never
        // premature; 8 WGs/XCD share one MALL fetch via L2)
        if (tn < T_ && tn >= 32) {
            const int sO = (tn - 32) & 63;
            const unsigned p32 = ((tn - 32) >> 6) & 1;
            loadfrag2x(sO, c32a - 6, c32b - 6, p32, true, h32a, h32b);
        }
    }
}

extern "C" void kernel_launch(void* const* d_in, const int* in_sizes, int n_in,
                              void* d_out, int out_size, void* d_ws, size_t ws_size,
                              hipStream_t stream) {
    const float* x   = (const float*)d_in[0];
    const float* Wih = (const float*)d_in[1];
    const float* Whh = (const float*)d_in[2];
    const float* bih = (const float*)d_in[3];
    const float* bhh = (const float*)d_in[4];
    float* out = (float*)d_out;

    u64* ring = (u64*)d_ws;   // 64*4*2048 u64 = 4 MB

    // LSB pattern 1 everywhere != gen-0 parity 0
    hipMemsetAsync(ring, 0x01, 64ull * 4 * 2048 * 8, stream);

    (void)hipFuncSetAttribute((const void*)lstm_persist,
                              hipFuncAttributeMaxDynamicSharedMemorySize, LDS_ALL);

    hipLaunchKernelGGL(lstm_persist, dim3(256), dim3(512), LDS_ALL, stream,
                       x, Wih, Whh, bih, bhh, out, ring);
}